// Round 2
// baseline (776.818 us; speedup 1.0000x reference)
//
#include <hip/hip_runtime.h>
#include <hip/hip_bf16.h>

// B=32, S=256, E=32, D=32. ALL DEVICE BUFFERS FP32 (reference dtypes).
// x = seq.reshape(32, 8192); Q/K/V = x @ W^T + b   (W: [8192,8192] row-major)
// attn = exp(QK^T)/(rowsum+1e-5) [no max-sub]; out = (attn @ V)/sqrt(32)
//
// GEMM strategy: HBM-bound on 805 MB of fp32 W. Use bf16 MFMA with hi/lo
// split (x = xh+xl, W = Wh+Wl, keep 3 of 4 product terms) for fp32-level
// accuracy at MFMA speed. W split inline (Sterbenz-exact residual).

#define FIN  8192
#define FOUT 8192
#define SD   8192

typedef __attribute__((ext_vector_type(8))) short bf16x8;   // 8 bf16 (4 VGPRs)
typedef __attribute__((ext_vector_type(4))) float f32x4;
typedef __attribute__((ext_vector_type(4))) short short4v;

static __device__ __forceinline__ short bf16_hi(float w, float& hf) {
    __hip_bfloat16 h = __float2bfloat16(w);      // RNE
    hf = __bfloat162float(h);
    return *(short*)&h;
}
static __device__ __forceinline__ short bf16_of(float w) {
    __hip_bfloat16 h = __float2bfloat16(w);
    return *(short*)&h;
}

// ---------------------------------------------------------------------------
// Kernel 0: split fp32 x -> bf16 hi + bf16 lo.  262144 elems = 65536 float4.
// ---------------------------------------------------------------------------
__global__ __launch_bounds__(256) void split_x(const float* __restrict__ x,
                                               short* __restrict__ xh,
                                               short* __restrict__ xl)
{
    const int i = blockIdx.x * 256 + threadIdx.x;      // float4 index
    float4 v = ((const float4*)x)[i];
    float wf[4] = {v.x, v.y, v.z, v.w};
    short h[4], l[4];
    #pragma unroll
    for (int j = 0; j < 4; ++j) {
        float hf;
        h[j] = bf16_hi(wf[j], hf);
        l[j] = bf16_of(wf[j] - hf);                    // wf-hf exact (Sterbenz)
    }
    ((short4v*)xh)[i] = short4v{h[0], h[1], h[2], h[3]};
    ((short4v*)xl)[i] = short4v{l[0], l[1], l[2], l[3]};
}

// ---------------------------------------------------------------------------
// Kernel 1: fused QKV GEMM.  768 blocks x 128 thr (2 waves) = 1536 wave-tiles
// = 3 matrices x 512 n-tiles(16).  Wave: C[32 x 16], K-loop step 32.
// 768 blocks = exactly 3 blocks/CU (even per-CU HBM load).
// ---------------------------------------------------------------------------
__global__ __launch_bounds__(128) void qkv_gemm(
    const short* __restrict__ xh, const short* __restrict__ xl,
    const float* __restrict__ Wq, const float* __restrict__ bq,
    const float* __restrict__ Wk, const float* __restrict__ bk,
    const float* __restrict__ Wv, const float* __restrict__ bv,
    float* __restrict__ outQ, float* __restrict__ outK, float* __restrict__ outV)
{
    const int wave = threadIdx.x >> 6;
    const int lane = threadIdx.x & 63;
    const int quad = lane >> 4;          // 0..3 -> k-octet
    const int r16  = lane & 15;

    const int tile  = blockIdx.x * 2 + wave;   // 0..1535
    const int which = tile >> 9;               // 0=Q 1=K 2=V
    const int nt    = tile & 511;

    const float* W; const float* bias; float* out;
    if (which == 0)      { W = Wq; bias = bq; out = outQ; }
    else if (which == 1) { W = Wk; bias = bk; out = outK; }
    else                 { W = Wv; bias = bv; out = outV; }

    const int n = nt * 16 + r16;               // owned W row / output column

    // A-frag layout (m89/m120): A[m=lane&15][k=quad*8+j]
    const bf16x8* Ah0 = (const bf16x8*)(xh + (size_t)r16        * FIN);
    const bf16x8* Ah1 = (const bf16x8*)(xh + (size_t)(16 + r16) * FIN);
    const bf16x8* Al0 = (const bf16x8*)(xl + (size_t)r16        * FIN);
    const bf16x8* Al1 = (const bf16x8*)(xl + (size_t)(16 + r16) * FIN);
    const float4* Wr  = (const float4*)(W + (size_t)n * FIN);   // row n

    f32x4 acc0 = {0.f, 0.f, 0.f, 0.f};
    f32x4 acc1 = {0.f, 0.f, 0.f, 0.f};

    #pragma unroll 2
    for (int i = 0; i < FIN / 32; ++i) {
        const int idx = i * 4 + quad;          // bf16x8 units (16B); float4 = idx*2
        bf16x8 ah0 = Ah0[idx];
        bf16x8 ah1 = Ah1[idx];
        bf16x8 al0 = Al0[idx];
        bf16x8 al1 = Al1[idx];
        float4 w0 = Wr[idx * 2];
        float4 w1 = Wr[idx * 2 + 1];

        float wf[8] = {w0.x, w0.y, w0.z, w0.w, w1.x, w1.y, w1.z, w1.w};
        short hb[8], lb[8];
        #pragma unroll
        for (int j = 0; j < 8; ++j) {
            float hf;
            hb[j] = bf16_hi(wf[j], hf);
            lb[j] = bf16_of(wf[j] - hf);
        }
        bf16x8 wh = {hb[0],hb[1],hb[2],hb[3],hb[4],hb[5],hb[6],hb[7]};
        bf16x8 wl = {lb[0],lb[1],lb[2],lb[3],lb[4],lb[5],lb[6],lb[7]};

        acc0 = __builtin_amdgcn_mfma_f32_16x16x32_bf16(ah0, wh, acc0, 0, 0, 0);
        acc0 = __builtin_amdgcn_mfma_f32_16x16x32_bf16(al0, wh, acc0, 0, 0, 0);
        acc0 = __builtin_amdgcn_mfma_f32_16x16x32_bf16(ah0, wl, acc0, 0, 0, 0);
        acc1 = __builtin_amdgcn_mfma_f32_16x16x32_bf16(ah1, wh, acc1, 0, 0, 0);
        acc1 = __builtin_amdgcn_mfma_f32_16x16x32_bf16(al1, wh, acc1, 0, 0, 0);
        acc1 = __builtin_amdgcn_mfma_f32_16x16x32_bf16(ah1, wl, acc1, 0, 0, 0);
    }

    // C/D layout (m89): col = lane&15 (=n), row = quad*4 + reg
    const float bvf = bias[n];
    #pragma unroll
    for (int i = 0; i < 4; ++i) {
        const int m = quad * 4 + i;
        out[(size_t)m        * FOUT + n] = acc0[i] + bvf;
        out[(size_t)(m + 16) * FOUT + n] = acc1[i] + bvf;
    }
}

// ---------------------------------------------------------------------------
// Kernel 2: attention, fp32, single pass (no max subtraction — faithful).
// grid = 32 batches x 8 row-tiles(32) = 256 blocks, 256 thr.
// ---------------------------------------------------------------------------
__global__ __launch_bounds__(256) void attention(
    const float* __restrict__ Qf, const float* __restrict__ Kf,
    const float* __restrict__ Vf, float* __restrict__ out)
{
    __shared__ float smem[16384];           // 64 KB: Ks | Vs, reused for partials
    float* Ks = smem;
    float* Vs = smem + SD;

    const int b     = blockIdx.x >> 3;
    const int stile = blockIdx.x & 7;
    const int tid   = threadIdx.x;

    const float* Kb = Kf + (size_t)b * SD;
    const float* Vb = Vf + (size_t)b * SD;
    for (int i = tid; i < SD / 4; i += 256) {
        ((float4*)Ks)[i] = ((const float4*)Kb)[i];
        ((float4*)Vs)[i] = ((const float4*)Vb)[i];
    }
    __syncthreads();

    const int srow  = tid & 31;
    const int chunk = tid >> 5;             // 0..7, each covers 32 t's
    const int s     = stile * 32 + srow;

    float q[32];
    const float* Qrow = Qf + (size_t)b * SD + (size_t)s * 32;
    #pragma unroll
    for (int d = 0; d < 32; ++d) q[d] = Qrow[d];

    float z[32];
    #pragma unroll
    for (int d = 0; d < 32; ++d) z[d] = 0.f;
    float den = 0.f;

    const int t0 = chunk * 32;
    for (int t = t0; t < t0 + 32; ++t) {
        const float* krow = Ks + t * 32;
        float scr = 0.f;
        #pragma unroll
        for (int d = 0; d < 32; ++d) scr += q[d] * krow[d];
        const float e = __expf(scr);
        den += e;
        const float* vrow = Vs + t * 32;
        #pragma unroll
        for (int d = 0; d < 32; ++d) z[d] += e * vrow[d];
    }

    __syncthreads();                        // done reading Ks/Vs
    float* pz   = smem;                     // [32][8][32]
    float* pden = smem + 8192;              // [32][8]
    #pragma unroll
    for (int d = 0; d < 32; ++d) pz[(srow * 8 + chunk) * 32 + d] = z[d];
    pden[srow * 8 + chunk] = den;
    __syncthreads();

    const int row = tid >> 3;               // 0..31
    const int dq  = tid & 7;                // 0..7
    float dsum = 0.f;
    #pragma unroll
    for (int c = 0; c < 8; ++c) dsum += pden[row * 8 + c];
    const float inv = 0.17677669529663687f / (dsum + 1e-5f);  // (1/sqrt(32))/(den+eps)

    const int so = stile * 32 + row;
    float* orow = out + (size_t)b * SD + (size_t)so * 32 + dq * 4;
    #pragma unroll
    for (int j = 0; j < 4; ++j) {
        float zz = 0.f;
        #pragma unroll
        for (int c = 0; c < 8; ++c) zz += pz[(row * 8 + c) * 32 + dq * 4 + j];
        orow[j] = zz * inv;
    }
}

// ---------------------------------------------------------------------------
extern "C" void kernel_launch(void* const* d_in, const int* in_sizes, int n_in,
                              void* d_out, int out_size, void* d_ws, size_t ws_size,
                              hipStream_t stream)
{
    const float* x  = (const float*)d_in[0];
    const float* Wq = (const float*)d_in[1];
    const float* bq = (const float*)d_in[2];
    const float* Wk = (const float*)d_in[3];
    const float* bk = (const float*)d_in[4];
    const float* Wv = (const float*)d_in[5];
    const float* bv = (const float*)d_in[6];
    float* out = (float*)d_out;

    // ws: xh[512KB] | xl[512KB] | Qf[1MB] | Kf[1MB] | Vf[1MB]  = 4 MB
    short* xh = (short*)d_ws;
    short* xl = xh + 262144;
    float* Qf = (float*)((char*)d_ws + (1u << 20));
    float* Kf = Qf + 262144;
    float* Vf = Kf + 262144;

    split_x  <<<256, 256, 0, stream>>>(x, xh, xl);
    qkv_gemm <<<768, 128, 0, stream>>>(xh, xl, Wq, bq, Wk, bk, Wv, bv, Qf, Kf, Vf);
    attention<<<256, 256, 0, stream>>>(Qf, Kf, Vf, out);
}